// Round 9
// baseline (163.873 us; speedup 1.0000x reference)
//
#include <hip/hip_runtime.h>
#include <math.h>
#include <stdint.h>

// NetVLAD: N=32, C=512, P=1024, K=64, ALPHA=100. Split-bf16 MFMA.
// R16 = R15 with the vlad K-half fix (R15 failed absmax 1.8e-3: both vlad
// MFMA fragment loads omitted the 8h K-half offset -> h=1 lanes duplicated
// h=0's p values: half the p positions double-counted, half dropped).
// Structure unchanged: ONE-STAGE fused kernel, no per-chunk phases.
// Evidence: R14 fused ran 85us with 66MB HBM fetch AND 85us fully cached
// -> NOT traffic-bound; MfmaUtil 4%, VALU 11%, clocks full -> cost is the
// lockstep {load,wait,stage,barrier,compute,barrier} phases. Here: stage
// whole 512c x 64p slab once (hi+lo planes resident in LDS), assign runs
// 8 chunks/wave with ZERO inner barriers, softmax, a2->LDS, vlad reads the
// SAME resident hi plane (no x re-read). ~6 barriers total.
#define ALPHA 100.0f
#define EPSN 1e-12f

typedef __attribute__((ext_vector_type(8))) short bf16x8;
typedef __attribute__((ext_vector_type(16))) float f32x16;
typedef __attribute__((ext_vector_type(4))) float f32x4;
typedef __attribute__((ext_vector_type(4))) unsigned int u32x4;

static __device__ __forceinline__ uint32_t f2bf(float f) {
    uint32_t u = __builtin_bit_cast(uint32_t, f);
    return (u + 0x7FFFu + ((u >> 16) & 1u)) >> 16;  // RNE
}
static __device__ __forceinline__ float bfhi(uint32_t u) {
    return __builtin_bit_cast(float, u & 0xFFFF0000u);
}

// ------- prep: v -> (vh, vl) bf16 split [k][c]; bias[k]; zero asum ---------
__global__ __launch_bounds__(64) void prep_kernel(const float* __restrict__ v,
                                                  unsigned short* __restrict__ vh,
                                                  unsigned short* __restrict__ vl,
                                                  float* __restrict__ bias,
                                                  float* __restrict__ az) {
    int k = blockIdx.x, lane = threadIdx.x;
    az[k * 64 + lane] = 0.f;
    const float* row = v + k * 512;
    float ssq = 0.f;
#pragma unroll
    for (int i = 0; i < 8; ++i) {
        int c = lane + 64 * i;
        float f = row[c];
        ssq = fmaf(f, f, ssq);
        uint32_t hi = f2bf(f);
        uint32_t lo = f2bf(f - __builtin_bit_cast(float, hi << 16));
        vh[k * 512 + c] = (unsigned short)hi;
        vl[k * 512 + c] = (unsigned short)lo;
    }
#pragma unroll
    for (int off = 32; off > 0; off >>= 1) ssq += __shfl_xor(ssq, off, 64);
    if (lane == 0) bias[k] = -ALPHA * sqrtf(ssq);
}

// =================== fused: assign + softmax + vlad partial =================
// grid 512 = (n, 64-p tile pt); block 512 = 8 waves.
__global__ __launch_bounds__(512) void fused_kernel(
    const float* __restrict__ x, const unsigned short* __restrict__ vh,
    const unsigned short* __restrict__ vl, const float* __restrict__ bias,
    float* __restrict__ pw, float* __restrict__ asum) {
    __shared__ uint32_t xallh[256 * 66];     // hi plane, c-pair rows, 64p cols (+2 pad)
    __shared__ uint32_t xallo[256 * 64];     // lo plane, stride 64 (reads are col-sweep)
    __shared__ float cmb[2][2][16][64];      // [kh][pj][reg][lane] c-half partials
    __shared__ unsigned short a2b[64 * 72];  // a2 bf16, p-major, row stride 72
    __shared__ float ssq_l[64];
    __shared__ float bias_l[64];
    __shared__ float xchm[2][2][32];         // [pj][kh]
    __shared__ float xchs[2][2][32];

    int tid = threadIdx.x, bx = blockIdx.x;
    int n = bx >> 4, pt = bx & 15, pblk = pt << 6;
    int l = tid & 63, w = tid >> 6;
    int h = l >> 5, cl = l & 31;

    if (tid < 64) {
        ssq_l[tid] = 0.f;
        bias_l[tid] = bias[tid];
    }

    // ---- stage: whole 512c x 64p slab -> LDS (one phase) ----
    int r0 = tid >> 4, q = tid & 15;  // c-pair base row r0, p-quad 4q
    const float* xgs = x + (size_t)n * 524288 + (size_t)(2 * r0) * 1024 + pblk + 4 * q;
    float4 va_[8], vb_[8];
#pragma unroll
    for (int i = 0; i < 8; ++i) {
        va_[i] = *(const float4*)(xgs + (size_t)i * 65536);
        vb_[i] = *(const float4*)(xgs + (size_t)i * 65536 + 1024);
    }
    __syncthreads();  // ssq_l/bias_l init visible
    f32x4 sq;
#pragma unroll
    for (int j = 0; j < 4; ++j) sq[j] = 0.f;
#pragma unroll
    for (int i = 0; i < 8; ++i) {
        int R = r0 + 32 * i;
        float fa[4] = {va_[i].x, va_[i].y, va_[i].z, va_[i].w};
        float fb[4] = {vb_[i].x, vb_[i].y, vb_[i].z, vb_[i].w};
        uint32_t hp[4];
        u32x4 lp;
#pragma unroll
        for (int j = 0; j < 4; ++j) {
            uint32_t h0 = f2bf(fa[j]);
            uint32_t l0 = f2bf(fa[j] - bfhi(h0 << 16));
            uint32_t h1 = f2bf(fb[j]);
            uint32_t l1 = f2bf(fb[j] - bfhi(h1 << 16));
            hp[j] = h0 | (h1 << 16);
            lp[j] = l0 | (l1 << 16);
            sq[j] = fmaf(fa[j], fa[j], fmaf(fb[j], fb[j], sq[j]));
        }
        *(uint2*)&xallh[R * 66 + 4 * q] = make_uint2(hp[0], hp[1]);
        *(uint2*)&xallh[R * 66 + 4 * q + 2] = make_uint2(hp[2], hp[3]);
        *(u32x4*)&xallo[R * 64 + 4 * q] = lp;
    }
#pragma unroll
    for (int j = 0; j < 4; ++j) atomicAdd(&ssq_l[4 * q + j], sq[j]);
    __syncthreads();  // slab + ssq ready

    // ---- assign: 8 waves = (kh, pj, ch); 8 chunks of 32c, NO barriers ----
    int kh = w & 1, pj = (w >> 1) & 1, ch = w >> 2;
    const unsigned short* vhg = vh + (size_t)(32 * kh + cl) * 512 + 256 * ch + 8 * h;
    const unsigned short* vlg = vl + (size_t)(32 * kh + cl) * 512 + 256 * ch + 8 * h;

    f32x16 accA, accB;
#pragma unroll
    for (int i = 0; i < 16; ++i) { accA[i] = 0.f; accB[i] = 0.f; }

    u32x4 pvh[2][2], pvl[2][2];
    pvh[0][0] = *(const u32x4*)(vhg);
    pvh[0][1] = *(const u32x4*)(vhg + 16);
    pvl[0][0] = *(const u32x4*)(vlg);
    pvl[0][1] = *(const u32x4*)(vlg + 16);
#pragma unroll
    for (int cc = 0; cc < 8; ++cc) {
        int cur = cc & 1;
        if (cc < 7) {
            pvh[cur ^ 1][0] = *(const u32x4*)(vhg + 32 * (cc + 1));
            pvh[cur ^ 1][1] = *(const u32x4*)(vhg + 32 * (cc + 1) + 16);
            pvl[cur ^ 1][0] = *(const u32x4*)(vlg + 32 * (cc + 1));
            pvl[cur ^ 1][1] = *(const u32x4*)(vlg + 32 * (cc + 1) + 16);
        }
#pragma unroll
        for (int s = 0; s < 2; ++s) {
            u32x4 bhp, blp;
#pragma unroll
            for (int q2 = 0; q2 < 4; ++q2) {
                int R = 128 * ch + 16 * cc + 8 * s + 4 * h + q2;
                bhp[q2] = xallh[R * 66 + 32 * pj + cl];
                blp[q2] = xallo[R * 64 + 32 * pj + cl];
            }
            bf16x8 ah = __builtin_bit_cast(bf16x8, pvh[cur][s]);
            bf16x8 al = __builtin_bit_cast(bf16x8, pvl[cur][s]);
            bf16x8 xh = __builtin_bit_cast(bf16x8, bhp);
            bf16x8 xl = __builtin_bit_cast(bf16x8, blp);
            f32x16& accr = s ? accB : accA;
            accr = __builtin_amdgcn_mfma_f32_32x32x16_bf16(ah, xh, accr, 0, 0, 0);
            accr = __builtin_amdgcn_mfma_f32_32x32x16_bf16(ah, xl, accr, 0, 0, 0);
            accr = __builtin_amdgcn_mfma_f32_32x32x16_bf16(al, xh, accr, 0, 0, 0);
        }
    }

    // ---- c-half combine + softmax (ch==0 waves) ----
    if (ch == 1) {
#pragma unroll
        for (int rr = 0; rr < 16; ++rr) cmb[kh][pj][rr][l] = accA[rr] + accB[rr];
    }
    __syncthreads();
    float e[16], m = -INFINITY, ssum = 0.f, sinv = 0.f;
    if (ch == 0) {
        float ssq = ssq_l[32 * pj + cl];
        sinv = 1.0f / fmaxf(sqrtf(ssq), EPSN);
        float twoAs = 2.0f * ALPHA * sinv;
#pragma unroll
        for (int rr = 0; rr < 16; ++rr) {
            int k = (rr & 3) + 8 * (rr >> 2) + 4 * h + 32 * kh;
            float dv = accA[rr] + accB[rr] + cmb[kh][pj][rr][l];
            float lv = fmaf(twoAs, dv, bias_l[k]);
            e[rr] = lv;
            m = fmaxf(m, lv);
        }
        m = fmaxf(m, __shfl_xor(m, 32, 64));
        if (l < 32) xchm[pj][kh][l] = m;
    }
    __syncthreads();
    if (ch == 0) {
        m = fmaxf(m, xchm[pj][1 - kh][cl]);
#pragma unroll
        for (int rr = 0; rr < 16; ++rr) {
            e[rr] = expf(e[rr] - m);
            ssum += e[rr];
        }
        ssum += __shfl_xor(ssum, 32, 64);
        if (l < 32) xchs[pj][kh][l] = ssum;
    }
    __syncthreads();
    if (ch == 0) {
        ssum += xchs[pj][1 - kh][cl];
        float rs = 1.0f / ssum;
        float a2s = rs * sinv;
#pragma unroll
        for (int rr = 0; rr < 16; ++rr) {
            int k = (rr & 3) + 8 * (rr >> 2) + 4 * h + 32 * kh;
            a2b[k * 72 + 32 * pj + cl] = (unsigned short)f2bf(e[rr] * a2s);
            float red = e[rr] * rs;
#pragma unroll
            for (int off = 1; off <= 16; off <<= 1) red += __shfl_xor(red, off, 64);
            if (cl == 0) atomicAdd(&asum[n * 64 + k], red);
        }
    }
    __syncthreads();  // a2b ready

    // ---- vlad: 8 waves = (kh, cq); K = 64 p; x from resident hi plane ----
    int cq = w >> 1;  // 0..3
    const uint32_t* a2w = (const uint32_t*)a2b;
    u32x4 af[4];
#pragma unroll
    for (int kc = 0; kc < 4; ++kc)  // K-half fix: +4*h (lane holds p = 16kc+8h+0..7)
        af[kc] = *(const u32x4*)&a2w[(32 * kh + cl) * 36 + 8 * kc + 4 * h];

    f32x16 va[4];
#pragma unroll
    for (int j = 0; j < 4; ++j)
#pragma unroll
        for (int i = 0; i < 16; ++i) va[j][i] = 0.f;

#pragma unroll
    for (int j = 0; j < 4; ++j) {
        int c = 128 * cq + 32 * j + cl;
        int cp = c >> 1;
        uint32_t odd = (uint32_t)(c & 1);
#pragma unroll
        for (int kc = 0; kc < 4; ++kc) {
            u32x4 bfv;
#pragma unroll
            for (int jj = 0; jj < 4; ++jj) {  // K-half fix: +8*h
                uint2 wp = *(const uint2*)&xallh[cp * 66 + 16 * kc + 8 * h + 2 * jj];
                uint32_t lo = (wp.x & 0xFFFFu) | (wp.y << 16);
                uint32_t hi = (wp.x >> 16) | (wp.y & 0xFFFF0000u);
                bfv[jj] = odd ? hi : lo;
            }
            va[j] = __builtin_amdgcn_mfma_f32_32x32x16_bf16(
                __builtin_bit_cast(bf16x8, af[kc]), __builtin_bit_cast(bf16x8, bfv),
                va[j], 0, 0, 0);
        }
    }
    // ---- store partials: pw[((n*16+pt)*64+k)*512 + c] ----
    float* pwb = pw + ((size_t)(n * 16 + pt) * 64) * 512;
#pragma unroll
    for (int j = 0; j < 4; ++j) {
        int c = 128 * cq + 32 * j + cl;
#pragma unroll
        for (int rr = 0; rr < 16; ++rr) {
            int k = (rr & 3) + 8 * (rr >> 2) + 4 * h + 32 * kh;
            pwb[(size_t)k * 512 + c] = va[j][rr];
        }
    }
}

// ====== combine: sum 16 p-partials, -asum*v, intra+global norms, write =====
// grid 32 = n; block 512.
__global__ __launch_bounds__(512) void combine_kernel(
    const float* __restrict__ pw, const float* __restrict__ asum,
    const float* __restrict__ vocabs, float* __restrict__ out) {
    __shared__ float lv[32768];  // val[k][c], 128 KB
    __shared__ float knorm_l[64];
    __shared__ float sc[64];
    __shared__ float tots;

    int n = blockIdx.x, tid = threadIdx.x;
    int kq = tid >> 7, tc = tid & 127;
    const float* pwn = pw + (size_t)n * 524288;

#pragma unroll
    for (int ki = 0; ki < 16; ++ki) {
        int k = kq * 16 + ki;
        float a = asum[n * 64 + k];
        float4 vv = *(const float4*)(vocabs + (size_t)k * 512 + 4 * tc);
        float4 s = make_float4(0.f, 0.f, 0.f, 0.f);
#pragma unroll
        for (int pt = 0; pt < 16; ++pt) {
            float4 p4 = *(const float4*)(pwn + (size_t)pt * 32768 + (size_t)k * 512 + 4 * tc);
            s.x += p4.x; s.y += p4.y; s.z += p4.z; s.w += p4.w;
        }
        s.x = fmaf(-a, vv.x, s.x);
        s.y = fmaf(-a, vv.y, s.y);
        s.z = fmaf(-a, vv.z, s.z);
        s.w = fmaf(-a, vv.w, s.w);
        *(float4*)&lv[k * 512 + 4 * tc] = s;
    }
    __syncthreads();
    {
        int k2 = tid >> 3, j = tid & 7;
        float t2 = 0.f;
#pragma unroll
        for (int i = 0; i < 16; ++i) {
            float4 v4 = *(const float4*)&lv[k2 * 512 + j * 64 + 4 * i];
            t2 += v4.x * v4.x + v4.y * v4.y + v4.z * v4.z + v4.w * v4.w;
        }
        t2 += __shfl_xor(t2, 1, 64);
        t2 += __shfl_xor(t2, 2, 64);
        t2 += __shfl_xor(t2, 4, 64);
        if (j == 0) knorm_l[k2] = t2;
    }
    __syncthreads();
    if (tid < 64) {
        float nk = sqrtf(knorm_l[tid]);
        float inv = 1.0f / fmaxf(nk, EPSN);
        sc[tid] = inv;
        float t = nk * inv;
        float t2 = t * t;
#pragma unroll
        for (int off = 32; off > 0; off >>= 1) t2 += __shfl_xor(t2, off, 64);
        if (tid == 0) tots = t2;
    }
    __syncthreads();
    float invt = 1.0f / fmaxf(sqrtf(tots), EPSN);
    float* on = out + (size_t)n * 32768;
#pragma unroll
    for (int i = 0; i < 64; ++i) {
        int idx = tid + 512 * i;
        on[idx] = lv[idx] * sc[idx >> 9] * invt;
    }
}

extern "C" void kernel_launch(void* const* d_in, const int* in_sizes, int n_in,
                              void* d_out, int out_size, void* d_ws, size_t ws_size,
                              hipStream_t stream) {
    const float* x = (const float*)d_in[0];       // [32,512,32,32]
    const float* vocabs = (const float*)d_in[1];  // [64,512]
    float* out = (float*)d_out;                   // [32, 32768]
    char* ws = (char*)d_ws;
    unsigned short* vh = (unsigned short*)(ws);            // 65536 B
    unsigned short* vl = (unsigned short*)(ws + 65536);    // 65536 B
    float* bias  = (float*)(ws + 131072);                  //   256 B
    float* asum  = (float*)(ws + 131328);                  //  8192 B
    float* pw    = (float*)(ws + 147712);                  // 64 MB partials

    prep_kernel<<<64, 64, 0, stream>>>(vocabs, vh, vl, bias, asum);
    fused_kernel<<<512, 512, 0, stream>>>(x, vh, vl, bias, pw, asum);
    combine_kernel<<<32, 512, 0, stream>>>(pw, asum, vocabs, out);
}